// Round 9
// baseline (2575.531 us; speedup 1.0000x reference)
//
#include <hip/hip_runtime.h>

// Fused 3-layer GCN (GS=7, H=144) + pool + fc, B=65536.  Round 9.
// R8 still lost ~45% of issue slots to the premix<->GEMM LDS round-trip
// (sXn/sXi staging, 6 sections/layer, 1.17e7 bank-conflict cycles). R9 fuses
// the premix into the GEMM: x stored 8-row-per-item (M=64), so each lane's
// B-fragment is bn = sum_j cN[j]*sX[item*8+j][kslice] — 7 broadcast LDS reads
// + pk-FMA with per-lane coeff registers (loaded once). sXn/sXi deleted;
// 2 barriers/layer with one long GEMM section. 16-half column swizzle per
// 8-row group kills the structural 4-way LDS bank aliasing.
// Algorithm (verified R7/R8): Xn=nA@x, Xi=iA@x; x_new=0.5*(relu(Xn@W1)+relu(Xi@W2)).
// wt layout (d_ws, unchanged): [l][p][nt][ks][lane][j8], n=nt*32+(lane&31)
//   (>=144 pad0), k=ks*16+(lane>>5)*8+j8. 1 KB per fragment, coalesced.
// MFMA: A[n][k]=Wt, B[k][m]=Xmix -> D[n][m];
// C/D: col=lane&31 (=m), row=(reg&3)+8*(reg>>2)+4*(lane>>5) (=n).
// LDS: sX 64x152 fp16 + sAh + adjd = 22.8 KB; occupancy VGPR-bound ~3 blocks/CU.

typedef _Float16 half8   __attribute__((ext_vector_type(8)));
typedef _Float16 half4_t __attribute__((ext_vector_type(4)));
typedef float    floatx16 __attribute__((ext_vector_type(16)));

constexpr int GS = 7;
constexpr int NI = 8;           // graphs per block
constexpr int H = 144;
constexpr int LSTRIDE = 2 * 5 * 9 * 512;  // 46080 halfs per layer
constexpr int WT_HALFS = 3 * LSTRIDE;     // 138240
constexpr int FRAGS = 3 * 90 * 64;        // thread-slices in prep (17280)

static __device__ inline half8 bc(_Float16 v) {
    half8 h = {v, v, v, v, v, v, v, v};
    return h;
}

// ---------------- prologue: weights -> fragment-linear fp16, g = fc2 @ fc1 ----------------
__global__ void prep_kernel(const float* __restrict__ w10, const float* __restrict__ w20,
                            const float* __restrict__ w11, const float* __restrict__ w21,
                            const float* __restrict__ w12, const float* __restrict__ w22,
                            const float* __restrict__ fc1, const float* __restrict__ fc2,
                            _Float16* __restrict__ wt, float* __restrict__ g)
{
    if (blockIdx.x == 68) {             // g = fc2 @ fc1 (both linear, no act)
        const int j = threadIdx.x;
        if (j < H) {
            float s = 0.f;
            for (int o = 0; o < 128; ++o) s = fmaf(fc2[o], fc1[o * H + j], s);
            g[j] = s;
        }
        return;
    }
    const int t = blockIdx.x * 256 + threadIdx.x;
    if (t >= FRAGS) return;
    const int l    = t / (90 * 64);
    const int r    = t - l * (90 * 64);
    const int frag = r >> 6;            // 0..89
    const int lane = r & 63;
    const int p    = frag / 45;         // 0 -> W1, 1 -> W2
    const int rem  = frag - p * 45;
    const int nt   = rem / 9;
    const int ks   = rem - nt * 9;
    const int n    = nt * 32 + (lane & 31);           // out-col 0..159
    const int k0   = ks * 16 + (lane >> 5) * 8;       // in-dim base
    const float* W = (l == 0) ? (p ? w20 : w10)
                   : (l == 1) ? (p ? w21 : w11)
                              : (p ? w22 : w12);
    const int K = (l == 0) ? 5 : 144;
    half8 h = bc((_Float16)0);
    #pragma unroll
    for (int j = 0; j < 8; ++j) {
        const int k = k0 + j;
        if (n < H && k < K) h[j] = (_Float16)W[k * H + n];   // lanes coalesce over n
    }
    *(half8*)(wt + (size_t)l * LSTRIDE + (size_t)frag * 512 + (size_t)lane * 8) = h;
}

// ---- GEMM with fused in-register premix ----
template<int NK, int NTB, int NTC>
__device__ __forceinline__ void do_gemm(const _Float16* __restrict__ wl,
                                        const half8 cN, const half8 cI,
                                        const int lane, const int rbase, const int swz,
                                        const _Float16 (*sX)[152],
                                        floatx16* acc1, floatx16* acc2)
{
    const int khi = (lane >> 5) * 8;
    #pragma unroll
    for (int t = 0; t < NTC; ++t) {
        #pragma unroll
        for (int i = 0; i < 16; ++i) { acc1[t][i] = 0.f; acc2[t][i] = 0.f; }
    }
    #pragma unroll
    for (int ks = 0; ks < NK; ++ks) {
        int c = ks * 16 + khi + swz;
        if (c >= H) c -= H;
        // fused premix: bn/bi for this lane's (m, k-slice)
        half8 bn = bc((_Float16)0), bi = bc((_Float16)0);
        #pragma unroll
        for (int j = 0; j < GS; ++j) {
            const half8 xj = *(const half8*)&sX[rbase + j][c];
            bn += bc(cN[j]) * xj;
            bi += bc(cI[j]) * xj;
        }
        #pragma unroll
        for (int t = 0; t < NTC; ++t) {
            const _Float16* a1 = wl + (size_t)(((NTB + t) * 9 + ks) * 512) + (size_t)lane * 8;
            acc1[t] = __builtin_amdgcn_mfma_f32_32x32x16_f16(*(const half8*)a1, bn, acc1[t], 0, 0, 0);
            acc2[t] = __builtin_amdgcn_mfma_f32_32x32x16_f16(*(const half8*)(a1 + 45 * 512), bi, acc2[t], 0, 0, 0);
        }
    }
}

// ---- epilogue: x_new = 0.5*(relu(acc1)+relu(acc2)) -> sX (swizzled cols) ----
template<int NTB, int NTC>
__device__ __forceinline__ void do_store(const floatx16* acc1, const floatx16* acc2,
                                         const int lane, const int mrow, const int swz,
                                         _Float16 (*sX)[152])
{
    #pragma unroll
    for (int t = 0; t < NTC; ++t) {
        #pragma unroll
        for (int q = 0; q < 4; ++q) {
            if (NTB + t < 4 || q < 2) {          // static: tile-4 cols >=144 dropped
                const int n0 = (NTB + t) * 32 + 4 * (lane >> 5) + 8 * q;
                int c = n0 + swz;
                if (c >= H) c -= H;
                half4_t h;
                #pragma unroll
                for (int i = 0; i < 4; ++i) {
                    const float v1 = acc1[t][4 * q + i] > 0.f ? acc1[t][4 * q + i] : 0.f;
                    const float v2 = acc2[t][4 * q + i] > 0.f ? acc2[t][4 * q + i] : 0.f;
                    h[i] = (_Float16)(0.5f * (v1 + v2));
                }
                *(half4_t*)&sX[mrow][c] = h;
            }
        }
    }
}

__global__ __launch_bounds__(256, 3)
void gcn_mfma(const float* __restrict__ ops, const float* __restrict__ adj,
              const float* __restrict__ nv,
              const _Float16* __restrict__ wt, const float* __restrict__ gw,
              float* __restrict__ out)
{
    __shared__ __align__(16) _Float16 sX[64][152];        // 19456 B, row = item*8+r
    __shared__ __align__(16) _Float16 sAh[NI][2][GS][8];  //  1792 B
    __shared__ float adjd[NI][GS][GS];                    //  1568 B   total 22816 B

    const int tid  = threadIdx.x;
    const int lane = tid & 63;
    const int wv   = tid >> 6;
    const int ibase = blockIdx.x * NI;

    // ---------------- per-block prologue: stage X (fp16, swizzled), adjacency ----------------
    if (tid < NI * GS) {
        const int item = tid / GS, r = tid % GS;
        const int row = item * 8 + r;
        const int s = (item & 3) * 16;                   // column swizzle for this row group
        const float* orow = ops + ((size_t)(ibase + item) * GS + r) * 5;
        half8 h = bc((_Float16)0);
        h[0] = (_Float16)orow[0]; h[1] = (_Float16)orow[1]; h[2] = (_Float16)orow[2];
        h[3] = (_Float16)orow[3]; h[4] = (_Float16)orow[4];
        *(half8*)&sX[row][s] = h;                        // logical k 0..7
        *(half8*)&sX[row][s + 8] = bc((_Float16)0);      // logical k 8..15 (layer-0 pad)

        const float* arow = adj + ((size_t)(ibase + item) * GS + r) * GS;
        float a[GS]; float sm = 0.f;
        #pragma unroll
        for (int c = 0; c < GS; ++c) { a[c] = arow[c] + (c == r ? 1.f : 0.f); sm += a[c]; }
        const float is = 1.f / sm;
        #pragma unroll
        for (int c = 0; c < GS; ++c) {
            const float v = a[c] * is;
            adjd[item][r][c] = v;
            sAh[item][0][r][c] = (_Float16)v;
        }
        sAh[item][0][r][7] = (_Float16)0.f;
    }
    __syncthreads();
    if (tid < NI * GS) {    // inv_norm_adj = row_normalize(adj_d^T)
        const int item = tid / GS, r = tid % GS;
        float v[GS]; float sm = 0.f;
        #pragma unroll
        for (int k = 0; k < GS; ++k) { v[k] = adjd[item][k][r]; sm += v[k]; }
        const float is = 1.f / sm;
        #pragma unroll
        for (int k = 0; k < GS; ++k) sAh[item][1][r][k] = (_Float16)(v[k] * is);
        sAh[item][1][r][7] = (_Float16)0.f;
    }
    __syncthreads();

    const int mt    = wv & 1;
    const int mrow  = mt * 32 + (lane & 31);      // 0..63, all valid (8-row items)
    const int rbase = mrow & ~7;                  // item's first row
    const int swz   = (mrow & 24) * 2;            // ((mrow>>3)&3)*16
    const int citem = mrow >> 3;
    const int cr    = (mrow & 7) < GS ? (mrow & 7) : (GS - 1);   // pad lanes: dup r=6
    const half8 cN  = *(const half8*)&sAh[citem][0][cr][0];
    const half8 cI  = *(const half8*)&sAh[citem][1][cr][0];

    floatx16 acc1[3], acc2[3];

    // ==================== layer 0 (K=16, one k-step) ====================
    if (wv < 2) do_gemm<1, 0, 3>(wt, cN, cI, lane, rbase, swz, sX, acc1, acc2);
    else        do_gemm<1, 3, 2>(wt, cN, cI, lane, rbase, swz, sX, acc1, acc2);
    __syncthreads();
    if (wv < 2) do_store<0, 3>(acc1, acc2, lane, mrow, swz, sX);
    else        do_store<3, 2>(acc1, acc2, lane, mrow, swz, sX);
    __syncthreads();

    // ==================== layers 1,2 (K=144, nine k-steps) ====================
    for (int layer = 1; layer < 3; ++layer) {
        const _Float16* wl = wt + (size_t)layer * LSTRIDE;
        if (wv < 2) do_gemm<9, 0, 3>(wl, cN, cI, lane, rbase, swz, sX, acc1, acc2);
        else        do_gemm<9, 3, 2>(wl, cN, cI, lane, rbase, swz, sX, acc1, acc2);
        __syncthreads();
        if (wv < 2) do_store<0, 3>(acc1, acc2, lane, mrow, swz, sX);
        else        do_store<3, 2>(acc1, acc2, lane, mrow, swz, sX);
        __syncthreads();
    }

    // ==================== pool + (fc2@fc1) dot ====================
    if (tid < NI * 16) {
        const int item = tid >> 4, part = tid & 15;
        const int s = (item & 3) * 16;
        float sm = 0.f;
        #pragma unroll
        for (int c = 0; c < 9; ++c) {
            const int j = part * 9 + c;
            int pc = j + s;
            if (pc >= H) pc -= H;
            const float gj = gw[j];
            #pragma unroll
            for (int i = 0; i < GS; ++i)
                sm = fmaf((float)sX[item * 8 + i][pc], gj, sm);
        }
        sm += __shfl_xor(sm, 1);
        sm += __shfl_xor(sm, 2);
        sm += __shfl_xor(sm, 4);
        sm += __shfl_xor(sm, 8);
        if (part == 0) out[ibase + item] = sm / nv[ibase + item];
    }
}

extern "C" void kernel_launch(void* const* d_in, const int* in_sizes, int n_in,
                              void* d_out, int out_size, void* d_ws, size_t ws_size,
                              hipStream_t stream) {
    const float* ops = (const float*)d_in[0];
    const float* adj = (const float*)d_in[1];
    const float* nv  = (const float*)d_in[2];
    const float* w10 = (const float*)d_in[3];
    const float* w20 = (const float*)d_in[4];
    const float* w11 = (const float*)d_in[5];
    const float* w21 = (const float*)d_in[6];
    const float* w12 = (const float*)d_in[7];
    const float* w22 = (const float*)d_in[8];
    const float* fc1 = (const float*)d_in[9];
    const float* fc2 = (const float*)d_in[10];

    _Float16* wt = (_Float16*)d_ws;                              // 276480 B
    float*    g  = (float*)((char*)d_ws + (size_t)WT_HALFS * 2); // 576 B

    prep_kernel<<<69, 256, 0, stream>>>(w10, w20, w11, w21, w12, w22,
                                        fc1, fc2, wt, g);
    gcn_mfma<<<65536 / NI, 256, 0, stream>>>(ops, adj, nv, wt, g, (float*)d_out);
}

// Round 10
// 337.483 us; speedup vs baseline: 7.6316x; 7.6316x over previous
//
#include <hip/hip_runtime.h>

// Fused 3-layer GCN (GS=7, H=144) + pool + fc, B=65536.  Round 10.
// R9's fused-premix algorithm was correct but SPILLED: floatx16 acc[3] arrays
// passed by pointer into helpers -> address-taken -> scratch (9 GB HBM traffic,
// VGPR_Count 84). R10 = same algorithm, spill-proof codegen: six NAMED
// accumulators in one straight-line inlined layer function, no arrays, no
// pointers to locals, wave-uniform internal branches. Barriers are inside the
// uniformly-called function (no divergent callsites).
// Algorithm (verified R7-R9): Xn=nA@x, Xi=iA@x; x_new=0.5*(relu(Xn@W1)+relu(Xi@W2));
// premix fused into the GEMM B-fragment build (7 broadcast LDS reads + pk-FMA).
// x stored 8-row-per-item (M=64, all lanes valid) with 16-half column swizzle
// per 8-row group (conflict-free premix reads, <=2-way stores).
// wt layout (d_ws): [l][p][nt][ks][lane][j8], n=nt*32+(lane&31) (>=144 pad0),
//   k=ks*16+(lane>>5)*8+j8. 1 KB per fragment, coalesced.
// MFMA: A[n][k]=Wt, B[k][m]=Xmix -> D[n][m];
// C/D: col=lane&31 (=m), row=(reg&3)+8*(reg>>2)+4*(lane>>5) (=n).
// LDS: sX 64x152 fp16 + sAh + adjd = 22.8 KB.

typedef _Float16 half8   __attribute__((ext_vector_type(8)));
typedef _Float16 half4_t __attribute__((ext_vector_type(4)));
typedef float    floatx16 __attribute__((ext_vector_type(16)));

constexpr int GS = 7;
constexpr int NI = 8;           // graphs per block
constexpr int H = 144;
constexpr int LSTRIDE = 2 * 5 * 9 * 512;  // 46080 halfs per layer
constexpr int WT_HALFS = 3 * LSTRIDE;     // 138240
constexpr int FRAGS = 3 * 90 * 64;        // thread-slices in prep (17280)

static __device__ inline half8 bc(_Float16 v) {
    half8 h = {v, v, v, v, v, v, v, v};
    return h;
}

// ---------------- prologue: weights -> fragment-linear fp16, g = fc2 @ fc1 ----------------
__global__ void prep_kernel(const float* __restrict__ w10, const float* __restrict__ w20,
                            const float* __restrict__ w11, const float* __restrict__ w21,
                            const float* __restrict__ w12, const float* __restrict__ w22,
                            const float* __restrict__ fc1, const float* __restrict__ fc2,
                            _Float16* __restrict__ wt, float* __restrict__ g)
{
    if (blockIdx.x == 68) {             // g = fc2 @ fc1 (both linear, no act)
        const int j = threadIdx.x;
        if (j < H) {
            float s = 0.f;
            for (int o = 0; o < 128; ++o) s = fmaf(fc2[o], fc1[o * H + j], s);
            g[j] = s;
        }
        return;
    }
    const int t = blockIdx.x * 256 + threadIdx.x;
    if (t >= FRAGS) return;
    const int l    = t / (90 * 64);
    const int r    = t - l * (90 * 64);
    const int frag = r >> 6;            // 0..89
    const int lane = r & 63;
    const int p    = frag / 45;         // 0 -> W1, 1 -> W2
    const int rem  = frag - p * 45;
    const int nt   = rem / 9;
    const int ks   = rem - nt * 9;
    const int n    = nt * 32 + (lane & 31);           // out-col 0..159
    const int k0   = ks * 16 + (lane >> 5) * 8;       // in-dim base
    const float* W = (l == 0) ? (p ? w20 : w10)
                   : (l == 1) ? (p ? w21 : w11)
                              : (p ? w22 : w12);
    const int K = (l == 0) ? 5 : 144;
    half8 h = bc((_Float16)0);
    #pragma unroll
    for (int j = 0; j < 8; ++j) {
        const int k = k0 + j;
        if (n < H && k < K) h[j] = (_Float16)W[k * H + n];   // lanes coalesce over n
    }
    *(half8*)(wt + (size_t)l * LSTRIDE + (size_t)frag * 512 + (size_t)lane * 8) = h;
}

// ---- epilogue for one tile: x_new = 0.5*(relu(a1)+relu(a2)) -> sX (by value!) ----
static __device__ __forceinline__ void store_tile(const floatx16 a1, const floatx16 a2,
                                                  const int nt, const int lane,
                                                  const int mrow, const int swz,
                                                  _Float16 (*sX)[152])
{
    #pragma unroll
    for (int q = 0; q < 4; ++q) {
        if (nt < 4 || q < 2) {                 // tile 4: cols >=144 dropped (uniform)
            const int n0 = nt * 32 + 4 * (lane >> 5) + 8 * q;
            int c = n0 + swz;
            if (c >= H) c -= H;
            half4_t h;
            #pragma unroll
            for (int i = 0; i < 4; ++i) {
                float v1 = a1[4 * q + i]; v1 = v1 > 0.f ? v1 : 0.f;
                float v2 = a2[4 * q + i]; v2 = v2 > 0.f ? v2 : 0.f;
                h[i] = (_Float16)(0.5f * (v1 + v2));
            }
            *(half4_t*)&sX[mrow][c] = h;
        }
    }
}

// ---- one full layer: fused premix+GEMM, barrier, epilogue, barrier ----
// Called by ALL threads (barriers inside are workgroup-uniform).
template<int NK>
static __device__ __forceinline__ void layer_pass(const _Float16* __restrict__ wl,
                                                  const half8 cN, const half8 cI,
                                                  const int lane, const int wv,
                                                  const int rbase, const int swz,
                                                  const int mrow, _Float16 (*sX)[152])
{
    const int  ntb   = (wv < 2) ? 0 : 3;
    const bool three = (wv < 2);
    const int  khi   = (lane >> 5) * 8;

    floatx16 p0, p1, p2, q0, q1, q2;       // named accumulators — never addressed
    #pragma unroll
    for (int i = 0; i < 16; ++i) {
        p0[i] = 0.f; p1[i] = 0.f; p2[i] = 0.f;
        q0[i] = 0.f; q1[i] = 0.f; q2[i] = 0.f;
    }

    #pragma unroll
    for (int ks = 0; ks < NK; ++ks) {
        int c = ks * 16 + khi + swz;
        if (c >= H) c -= H;
        // fused premix: B-fragments for this lane's (m, k-slice)
        half8 bn = bc((_Float16)0), bi = bc((_Float16)0);
        #pragma unroll
        for (int j = 0; j < GS; ++j) {
            const half8 xj = *(const half8*)&sX[rbase + j][c];
            bn += bc(cN[j]) * xj;
            bi += bc(cI[j]) * xj;
        }
        const _Float16* b0 = wl + (size_t)((ntb * 9 + ks) * 512) + (size_t)lane * 8;
        p0 = __builtin_amdgcn_mfma_f32_32x32x16_f16(*(const half8*)b0,                bn, p0, 0, 0, 0);
        q0 = __builtin_amdgcn_mfma_f32_32x32x16_f16(*(const half8*)(b0 + 45 * 512),   bi, q0, 0, 0, 0);
        p1 = __builtin_amdgcn_mfma_f32_32x32x16_f16(*(const half8*)(b0 + 9 * 512),    bn, p1, 0, 0, 0);
        q1 = __builtin_amdgcn_mfma_f32_32x32x16_f16(*(const half8*)(b0 + 54 * 512),   bi, q1, 0, 0, 0);
        if (three) {
            p2 = __builtin_amdgcn_mfma_f32_32x32x16_f16(*(const half8*)(b0 + 18 * 512), bn, p2, 0, 0, 0);
            q2 = __builtin_amdgcn_mfma_f32_32x32x16_f16(*(const half8*)(b0 + 63 * 512), bi, q2, 0, 0, 0);
        }
    }

    __syncthreads();   // all premix reads of old sX done
    store_tile(p0, q0, ntb + 0, lane, mrow, swz, sX);
    store_tile(p1, q1, ntb + 1, lane, mrow, swz, sX);
    if (three) store_tile(p2, q2, ntb + 2, lane, mrow, swz, sX);
    __syncthreads();   // x_new visible
}

__global__ __launch_bounds__(256, 3)
void gcn_mfma(const float* __restrict__ ops, const float* __restrict__ adj,
              const float* __restrict__ nv,
              const _Float16* __restrict__ wt, const float* __restrict__ gw,
              float* __restrict__ out)
{
    __shared__ __align__(16) _Float16 sX[64][152];        // 19456 B, row = item*8+r
    __shared__ __align__(16) _Float16 sAh[NI][2][GS][8];  //  1792 B
    __shared__ float adjd[NI][GS][GS];                    //  1568 B   total 22816 B

    const int tid  = threadIdx.x;
    const int lane = tid & 63;
    const int wv   = tid >> 6;
    const int ibase = blockIdx.x * NI;

    // ---------------- per-block prologue: stage X (fp16, swizzled), adjacency ----------------
    if (tid < NI * GS) {
        const int item = tid / GS, r = tid % GS;
        const int row = item * 8 + r;
        const int s = (item & 3) * 16;                   // column swizzle for this row group
        const float* orow = ops + ((size_t)(ibase + item) * GS + r) * 5;
        half8 h = bc((_Float16)0);
        h[0] = (_Float16)orow[0]; h[1] = (_Float16)orow[1]; h[2] = (_Float16)orow[2];
        h[3] = (_Float16)orow[3]; h[4] = (_Float16)orow[4];
        *(half8*)&sX[row][s] = h;                        // logical k 0..7
        *(half8*)&sX[row][s + 8] = bc((_Float16)0);      // logical k 8..15 (layer-0 pad)

        const float* arow = adj + ((size_t)(ibase + item) * GS + r) * GS;
        float a[GS]; float sm = 0.f;
        #pragma unroll
        for (int c = 0; c < GS; ++c) { a[c] = arow[c] + (c == r ? 1.f : 0.f); sm += a[c]; }
        const float is = 1.f / sm;
        #pragma unroll
        for (int c = 0; c < GS; ++c) {
            const float v = a[c] * is;
            adjd[item][r][c] = v;
            sAh[item][0][r][c] = (_Float16)v;
        }
        sAh[item][0][r][7] = (_Float16)0.f;
    }
    __syncthreads();
    if (tid < NI * GS) {    // inv_norm_adj = row_normalize(adj_d^T)
        const int item = tid / GS, r = tid % GS;
        float v[GS]; float sm = 0.f;
        #pragma unroll
        for (int k = 0; k < GS; ++k) { v[k] = adjd[item][k][r]; sm += v[k]; }
        const float is = 1.f / sm;
        #pragma unroll
        for (int k = 0; k < GS; ++k) sAh[item][1][r][k] = (_Float16)(v[k] * is);
        sAh[item][1][r][7] = (_Float16)0.f;
    }
    __syncthreads();

    const int mt    = wv & 1;
    const int mrow  = mt * 32 + (lane & 31);      // 0..63, all valid (8-row items)
    const int rbase = mrow & ~7;                  // item's first row
    const int swz   = (mrow & 24) * 2;            // ((mrow>>3)&3)*16
    const int citem = mrow >> 3;
    const int cr    = (mrow & 7) < GS ? (mrow & 7) : (GS - 1);   // pad rows: dup r=6
    const half8 cN  = *(const half8*)&sAh[citem][0][cr][0];
    const half8 cI  = *(const half8*)&sAh[citem][1][cr][0];

    // ==================== 3 layers ====================
    layer_pass<1>(wt,                          cN, cI, lane, wv, rbase, swz, mrow, sX);
    layer_pass<9>(wt + (size_t)1 * LSTRIDE,    cN, cI, lane, wv, rbase, swz, mrow, sX);
    layer_pass<9>(wt + (size_t)2 * LSTRIDE,    cN, cI, lane, wv, rbase, swz, mrow, sX);

    // ==================== pool + (fc2@fc1) dot ====================
    if (tid < NI * 16) {
        const int item = tid >> 4, part = tid & 15;
        const int s = (item & 3) * 16;
        float sm = 0.f;
        #pragma unroll
        for (int c = 0; c < 9; ++c) {
            const int j = part * 9 + c;
            int pc = j + s;
            if (pc >= H) pc -= H;
            const float gj = gw[j];
            #pragma unroll
            for (int i = 0; i < GS; ++i)
                sm = fmaf((float)sX[item * 8 + i][pc], gj, sm);
        }
        sm += __shfl_xor(sm, 1);
        sm += __shfl_xor(sm, 2);
        sm += __shfl_xor(sm, 4);
        sm += __shfl_xor(sm, 8);
        if (part == 0) out[ibase + item] = sm / nv[ibase + item];
    }
}

extern "C" void kernel_launch(void* const* d_in, const int* in_sizes, int n_in,
                              void* d_out, int out_size, void* d_ws, size_t ws_size,
                              hipStream_t stream) {
    const float* ops = (const float*)d_in[0];
    const float* adj = (const float*)d_in[1];
    const float* nv  = (const float*)d_in[2];
    const float* w10 = (const float*)d_in[3];
    const float* w20 = (const float*)d_in[4];
    const float* w11 = (const float*)d_in[5];
    const float* w21 = (const float*)d_in[6];
    const float* w12 = (const float*)d_in[7];
    const float* w22 = (const float*)d_in[8];
    const float* fc1 = (const float*)d_in[9];
    const float* fc2 = (const float*)d_in[10];

    _Float16* wt = (_Float16*)d_ws;                              // 276480 B
    float*    g  = (float*)((char*)d_ws + (size_t)WT_HALFS * 2); // 576 B

    prep_kernel<<<69, 256, 0, stream>>>(w10, w20, w11, w21, w12, w22,
                                        fc1, fc2, wt, g);
    gcn_mfma<<<65536 / NI, 256, 0, stream>>>(ops, adj, nv, wt, g, (float*)d_out);
}

// Round 11
// 268.796 us; speedup vs baseline: 9.5817x; 1.2555x over previous
//
#include <hip/hip_runtime.h>

// Fused 3-layer GCN (GS=7, H=144) + pool + fc, B=65536.  Round 11.
// R8 (218 us, best) re-fetched every weight fragment TWICE per block (once
// per m-tile wave pair): 456 KB/block -> ~14.6 MB/CU via L2 ~= 108 us of its
// wall. R11 = R8 with single-fetch wave ownership: wave w owns n-tile w for
// BOTH m-tiles and BOTH p (4 accs); tile 4 is split by m-tile across waves
// 2/3 (6 accs, same budget R8 proved at 3 blocks/CU). Each wave holds both
// p-halves of its outputs -> combine in-register, 2 barriers/layer unchanged.
// Per-block A-traffic 456 -> 228 KB. Numerics identical to R8.
// Algorithm (verified R7-R10): Xn=nA@x, Xi=iA@x (cooperative premix to LDS);
//   x_new = 0.5*(relu(Xn@W1) + relu(Xi@W2)) as MFMA epilogue.
// wt layout (d_ws): [l][p][nt][ks][lane][j8], n=nt*32+(lane&31) (>=144 pad0),
//   k=ks*16+(lane>>5)*8+j8. 1 KB per fragment, coalesced.
// MFMA: A[n][k]=Wt, B[k][m]=Xmix -> D[n][m];
// C/D: col=lane&31 (=m), row=(reg&3)+8*(reg>>2)+4*(lane>>5) (=n).
// LDS: sX + sXn + sXi (56x152 fp16) + sAh = 52.9 KB -> 3 blocks/CU.

typedef _Float16 half8   __attribute__((ext_vector_type(8)));
typedef _Float16 half4_t __attribute__((ext_vector_type(4)));
typedef float    floatx16 __attribute__((ext_vector_type(16)));

constexpr int GS = 7;
constexpr int NI = 8;           // graphs per block
constexpr int MROWS = NI * GS;  // 56
constexpr int H = 144;
constexpr int LSTRIDE = 2 * 5 * 9 * 512;  // 46080 halfs per layer
constexpr int WT_HALFS = 3 * LSTRIDE;     // 138240
constexpr int FRAGS = 3 * 90 * 64;        // thread-slices in prep (17280)

static __device__ inline half8 bc(_Float16 v) {
    half8 h = {v, v, v, v, v, v, v, v};
    return h;
}

// ---------------- prologue: weights -> fragment-linear fp16, g = fc2 @ fc1 ----------------
__global__ void prep_kernel(const float* __restrict__ w10, const float* __restrict__ w20,
                            const float* __restrict__ w11, const float* __restrict__ w21,
                            const float* __restrict__ w12, const float* __restrict__ w22,
                            const float* __restrict__ fc1, const float* __restrict__ fc2,
                            _Float16* __restrict__ wt, float* __restrict__ g)
{
    if (blockIdx.x == 68) {             // g = fc2 @ fc1 (both linear, no act)
        const int j = threadIdx.x;
        if (j < H) {
            float s = 0.f;
            for (int o = 0; o < 128; ++o) s = fmaf(fc2[o], fc1[o * H + j], s);
            g[j] = s;
        }
        return;
    }
    const int t = blockIdx.x * 256 + threadIdx.x;
    if (t >= FRAGS) return;
    const int l    = t / (90 * 64);
    const int r    = t - l * (90 * 64);
    const int frag = r >> 6;            // 0..89
    const int lane = r & 63;
    const int p    = frag / 45;         // 0 -> W1, 1 -> W2
    const int rem  = frag - p * 45;
    const int nt   = rem / 9;
    const int ks   = rem - nt * 9;
    const int n    = nt * 32 + (lane & 31);           // out-col 0..159
    const int k0   = ks * 16 + (lane >> 5) * 8;       // in-dim base
    const float* W = (l == 0) ? (p ? w20 : w10)
                   : (l == 1) ? (p ? w21 : w11)
                              : (p ? w22 : w12);
    const int K = (l == 0) ? 5 : 144;
    half8 h = bc((_Float16)0);
    #pragma unroll
    for (int j = 0; j < 8; ++j) {
        const int k = k0 + j;
        if (n < H && k < K) h[j] = (_Float16)W[k * H + n];   // lanes coalesce over n
    }
    *(half8*)(wt + (size_t)l * LSTRIDE + (size_t)frag * 512 + (size_t)lane * 8) = h;
}

// ---- one full layer: cooperative premix, dual-m GEMM, in-register epilogue ----
// Called uniformly by all 256 threads; barriers are workgroup-uniform.
template<int NK, int CB>
static __device__ __forceinline__ void layer_pass(const _Float16* __restrict__ wl,
                                                  const int tid, const int lane, const int wv,
                                                  _Float16 (*sX)[152],
                                                  _Float16 (*sXn)[152], _Float16 (*sXi)[152],
                                                  const _Float16 (*sAh)[2][GS][8])
{
    // ---- cooperative premix: Xn = nA@x, Xi = iA@x (done once per block) ----
    for (int u = tid; u < MROWS * CB; u += 256) {
        const int row = u / CB, cb = u - row * CB;
        const int item = row / GS, rr = row - item * GS;
        const int c0 = cb * 8;
        const half8 aN = *(const half8*)&sAh[item][0][rr][0];
        const half8 aI = *(const half8*)&sAh[item][1][rr][0];
        half8 an = bc((_Float16)0), ai = bc((_Float16)0);
        #pragma unroll
        for (int j = 0; j < GS; ++j) {
            const half8 xj = *(const half8*)&sX[item * GS + j][c0];
            an += bc(aN[j]) * xj;
            ai += bc(aI[j]) * xj;
        }
        *(half8*)&sXn[row][c0] = an;
        *(half8*)&sXi[row][c0] = ai;
    }
    __syncthreads();   // B1: Xn/Xi ready; all reads of old sX complete

    // ---- wave-owned GEMM: nt = wv (both m, both p); waves 2/3 add nt4 (m = wv-2)
    const int  nt    = wv;                 // wave-uniform
    const bool extra = (wv >= 2);
    const int  em    = wv & 1;             // nt4 m-tile for waves 2(m0)/3(m1)
    const int  khi   = (lane >> 5) * 8;
    const int  r0    = lane & 31;          // m-tile 0 row
    const int  r1    = 32 + r0;            // m-tile 1 row (>=56 invalid)
    const int  r1c   = (r1 < MROWS) ? r1 : (MROWS - 1);   // clamped LDS read

    floatx16 a1m0, a1m1, a2m0, a2m1, e1, e2;   // named accs — never addressed
    #pragma unroll
    for (int i = 0; i < 16; ++i) {
        a1m0[i] = 0.f; a1m1[i] = 0.f; a2m0[i] = 0.f; a2m1[i] = 0.f;
        e1[i] = 0.f; e2[i] = 0.f;
    }

    #pragma unroll
    for (int ks = 0; ks < NK; ++ks) {
        const int c = ks * 16 + khi;
        const half8 bn0 = *(const half8*)&sXn[r0][c];
        const half8 bn1 = *(const half8*)&sXn[r1c][c];
        const half8 bi0 = *(const half8*)&sXi[r0][c];
        const half8 bi1 = *(const half8*)&sXi[r1c][c];
        const _Float16* f1 = wl + (size_t)((nt * 9 + ks) * 512) + (size_t)lane * 8;
        const half8 A1 = *(const half8*)f1;              // p=0 (W1)
        const half8 A2 = *(const half8*)(f1 + 45 * 512); // p=1 (W2)
        a1m0 = __builtin_amdgcn_mfma_f32_32x32x16_f16(A1, bn0, a1m0, 0, 0, 0);
        a1m1 = __builtin_amdgcn_mfma_f32_32x32x16_f16(A1, bn1, a1m1, 0, 0, 0);
        a2m0 = __builtin_amdgcn_mfma_f32_32x32x16_f16(A2, bi0, a2m0, 0, 0, 0);
        a2m1 = __builtin_amdgcn_mfma_f32_32x32x16_f16(A2, bi1, a2m1, 0, 0, 0);
        if (extra) {
            const _Float16* f4 = wl + (size_t)((36 + ks) * 512) + (size_t)lane * 8;
            const half8 E1 = *(const half8*)f4;
            const half8 E2 = *(const half8*)(f4 + 45 * 512);
            e1 = __builtin_amdgcn_mfma_f32_32x32x16_f16(E1, em ? bn1 : bn0, e1, 0, 0, 0);
            e2 = __builtin_amdgcn_mfma_f32_32x32x16_f16(E2, em ? bi1 : bi0, e2, 0, 0, 0);
        }
    }

    // ---- epilogue: x_new = 0.5*(relu(P1)+relu(P2)) straight to sX ----
    // nt tile (nt<4 -> all 4 q valid, cols nt*32..nt*32+31 < 128)
    #pragma unroll
    for (int q = 0; q < 4; ++q) {
        const int n0 = nt * 32 + 4 * (lane >> 5) + 8 * q;
        half4_t h0, h1;
        #pragma unroll
        for (int i = 0; i < 4; ++i) {
            float v1 = a1m0[4 * q + i]; v1 = v1 > 0.f ? v1 : 0.f;
            float v2 = a2m0[4 * q + i]; v2 = v2 > 0.f ? v2 : 0.f;
            h0[i] = (_Float16)(0.5f * (v1 + v2));
            float w1 = a1m1[4 * q + i]; w1 = w1 > 0.f ? w1 : 0.f;
            float w2 = a2m1[4 * q + i]; w2 = w2 > 0.f ? w2 : 0.f;
            h1[i] = (_Float16)(0.5f * (w1 + w2));
        }
        *(half4_t*)&sX[r0][n0] = h0;                    // m0 rows 0..31 always valid
        if (r0 < MROWS - 32) *(half4_t*)&sX[r1][n0] = h1;  // m1 rows 32..55
    }
    if (extra) {       // nt4: cols 128..143 (q<2 only), rows em*32 + r0
        #pragma unroll
        for (int q = 0; q < 2; ++q) {
            const int n0 = 128 + 4 * (lane >> 5) + 8 * q;
            half4_t h;
            #pragma unroll
            for (int i = 0; i < 4; ++i) {
                float v1 = e1[4 * q + i]; v1 = v1 > 0.f ? v1 : 0.f;
                float v2 = e2[4 * q + i]; v2 = v2 > 0.f ? v2 : 0.f;
                h[i] = (_Float16)(0.5f * (v1 + v2));
            }
            const int rr = em * 32 + r0;
            if (rr < MROWS) *(half4_t*)&sX[rr][n0] = h;
        }
    }
    __syncthreads();   // B2: x_new visible for next premix / pool
}

__global__ __launch_bounds__(256, 3)
void gcn_mfma(const float* __restrict__ ops, const float* __restrict__ adj,
              const float* __restrict__ nv,
              const _Float16* __restrict__ wt, const float* __restrict__ gw,
              float* __restrict__ out)
{
    __shared__ __align__(16) _Float16 sX [MROWS][152];   // 17024 B
    __shared__ __align__(16) _Float16 sXn[MROWS][152];   // 17024 B
    __shared__ __align__(16) _Float16 sXi[MROWS][152];   // 17024 B
    __shared__ __align__(16) _Float16 sAh[NI][2][GS][8]; //  1792 B  total 52864 B

    float (*adjd)[GS][GS] = (float(*)[GS][GS])&sXn[0][0];   // prologue-only scratch

    const int tid  = threadIdx.x;
    const int lane = tid & 63;
    const int wv   = tid >> 6;
    const int ibase = blockIdx.x * NI;

    // ---------------- per-block prologue: stage X (fp16), adjacency matrices ----------------
    if (tid < MROWS) {
        const int item = tid / GS, r = tid % GS;
        const float* orow = ops + ((size_t)(ibase + item) * GS + r) * 5;
        half8 h = bc((_Float16)0);
        h[0] = (_Float16)orow[0]; h[1] = (_Float16)orow[1]; h[2] = (_Float16)orow[2];
        h[3] = (_Float16)orow[3]; h[4] = (_Float16)orow[4];
        *(half8*)&sX[tid][0] = h;
        *(half8*)&sX[tid][8] = bc((_Float16)0);   // layer-0 K pad (k=5..15)

        const float* arow = adj + ((size_t)(ibase + item) * GS + r) * GS;
        float a[GS]; float sm = 0.f;
        #pragma unroll
        for (int c = 0; c < GS; ++c) { a[c] = arow[c] + (c == r ? 1.f : 0.f); sm += a[c]; }
        const float is = 1.f / sm;
        #pragma unroll
        for (int c = 0; c < GS; ++c) {
            const float v = a[c] * is;
            adjd[item][r][c] = v;
            sAh[item][0][r][c] = (_Float16)v;
        }
        sAh[item][0][r][7] = (_Float16)0.f;
    }
    __syncthreads();
    if (tid < MROWS) {    // inv_norm_adj = row_normalize(adj_d^T)
        const int item = tid / GS, r = tid % GS;
        float v[GS]; float sm = 0.f;
        #pragma unroll
        for (int k = 0; k < GS; ++k) { v[k] = adjd[item][k][r]; sm += v[k]; }
        const float is = 1.f / sm;
        #pragma unroll
        for (int k = 0; k < GS; ++k) sAh[item][1][r][k] = (_Float16)(v[k] * is);
        sAh[item][1][r][7] = (_Float16)0.f;
    }
    __syncthreads();

    // ==================== 3 layers ====================
    layer_pass<1, 2>(wt,                        tid, lane, wv, sX, sXn, sXi, sAh);
    layer_pass<9, 18>(wt + (size_t)1 * LSTRIDE, tid, lane, wv, sX, sXn, sXi, sAh);
    layer_pass<9, 18>(wt + (size_t)2 * LSTRIDE, tid, lane, wv, sX, sXn, sXi, sAh);

    // ==================== pool + (fc2@fc1) dot ====================
    if (tid < NI * 16) {
        const int item = tid >> 4, part = tid & 15;
        float s = 0.f;
        #pragma unroll
        for (int c = 0; c < 9; ++c) {
            const int j = part * 9 + c;
            const float gj = gw[j];
            #pragma unroll
            for (int i = 0; i < GS; ++i)
                s = fmaf((float)sX[item * GS + i][j], gj, s);
        }
        s += __shfl_xor(s, 1);
        s += __shfl_xor(s, 2);
        s += __shfl_xor(s, 4);
        s += __shfl_xor(s, 8);
        if (part == 0) out[ibase + item] = s / nv[ibase + item];
    }
}

extern "C" void kernel_launch(void* const* d_in, const int* in_sizes, int n_in,
                              void* d_out, int out_size, void* d_ws, size_t ws_size,
                              hipStream_t stream) {
    const float* ops = (const float*)d_in[0];
    const float* adj = (const float*)d_in[1];
    const float* nv  = (const float*)d_in[2];
    const float* w10 = (const float*)d_in[3];
    const float* w20 = (const float*)d_in[4];
    const float* w11 = (const float*)d_in[5];
    const float* w21 = (const float*)d_in[6];
    const float* w12 = (const float*)d_in[7];
    const float* w22 = (const float*)d_in[8];
    const float* fc1 = (const float*)d_in[9];
    const float* fc2 = (const float*)d_in[10];

    _Float16* wt = (_Float16*)d_ws;                              // 276480 B
    float*    g  = (float*)((char*)d_ws + (size_t)WT_HALFS * 2); // 576 B

    prep_kernel<<<69, 256, 0, stream>>>(w10, w20, w11, w21, w12, w22,
                                        fc1, fc2, wt, g);
    gcn_mfma<<<65536 / NI, 256, 0, stream>>>(ops, adj, nv, wt, g, (float*)d_out);
}